// Round 3
// baseline (376.111 us; speedup 1.0000x reference)
//
#include <hip/hip_runtime.h>
#include <hip/hip_bf16.h>

using bf16 = __hip_bfloat16;
typedef __attribute__((ext_vector_type(8))) short bf16x8;
typedef __attribute__((ext_vector_type(4))) float f32x4;

// Problem constants
constexpr int S = 8, I = 64, M = 256, N = 16384;
constexpr int SM = S * M;       // 2048
constexpr int MODROW = S * I;   // 512  (fp32 elements per modulation row)
constexpr int OUTROW = S * M;   // 2048 (fp32 elements per output row)

__device__ __forceinline__ short f2bf_s(float f) {
    union { bf16 b; short s; } u; u.b = __float2bfloat16(f); return u.s;
}
// load 8 consecutive fp32, convert to a bf16x8 MFMA fragment slice
__device__ __forceinline__ bf16x8 load8_f32_to_bf16(const float* p) {
    const float4* q = (const float4*)p;
    float4 x = q[0], y = q[1];
    bf16x8 r;
    r[0] = f2bf_s(x.x); r[1] = f2bf_s(x.y); r[2] = f2bf_s(x.z); r[3] = f2bf_s(x.w);
    r[4] = f2bf_s(y.x); r[5] = f2bf_s(y.y); r[6] = f2bf_s(y.z); r[7] = f2bf_s(y.w);
    return r;
}

__device__ __forceinline__ float sigmoid_f(float x) {
    return __builtin_amdgcn_rcpf(1.f + __expf(-x));
}
__device__ __forceinline__ float tanh_f(float x) {
    return 2.f * __builtin_amdgcn_rcpf(1.f + __expf(-2.f * x)) - 1.f;
}

// ---------------------------------------------------------------------------
// Kernel 1: fold Wx/bx/h0 into effective per-gate weights + biases (all fp32 in).
//   Weff[s][m][g][k] = sum_j WG[s][m][j] * Wx[s][j][k]   (stored bf16)
//   beff[g][sm]      = bG[sm] + sum_j WG[sm][j]*bx[s][j] + sum_j WG[sm][M+j]*h0[s][j]
// grid = S*M blocks, 256 threads: wave = gate, lane = k.
// ---------------------------------------------------------------------------
__global__ __launch_bounds__(256) void precompute_kernel(
    const float* __restrict__ Wx, const float* __restrict__ bx,
    const float* __restrict__ Wi, const float* __restrict__ bi,
    const float* __restrict__ Wf, const float* __restrict__ bfv,
    const float* __restrict__ Wg, const float* __restrict__ bg,
    const float* __restrict__ Wo, const float* __restrict__ bo,
    const float* __restrict__ h0,
    bf16* __restrict__ Weff, float* __restrict__ beff)
{
    const int sm = blockIdx.x;          // s*256 + m
    const int s  = sm >> 8;
    const int g  = threadIdx.x >> 6;    // gate = wave id
    const int k  = threadIdx.x & 63;    // I-dim index

    const float* WG = (g == 0) ? Wi : (g == 1) ? Wf : (g == 2) ? Wg : Wo;
    const float* bG = (g == 0) ? bi : (g == 1) ? bfv : (g == 2) ? bg : bo;

    const float* wrow = WG + (size_t)sm * 512;            // WG[s][m][0..512)
    const float* wxs  = Wx + (size_t)s * (256 * 64) + k;  // Wx[s][j][k], stride 64

    float acc = 0.f;
    for (int j8 = 0; j8 < 256; j8 += 8) {
        const float4* q = (const float4*)(wrow + j8);   // wave-uniform -> s_load
        float4 w0 = q[0], w1 = q[1];
        acc = fmaf(w0.x, wxs[(size_t)(j8 + 0) * 64], acc);
        acc = fmaf(w0.y, wxs[(size_t)(j8 + 1) * 64], acc);
        acc = fmaf(w0.z, wxs[(size_t)(j8 + 2) * 64], acc);
        acc = fmaf(w0.w, wxs[(size_t)(j8 + 3) * 64], acc);
        acc = fmaf(w1.x, wxs[(size_t)(j8 + 4) * 64], acc);
        acc = fmaf(w1.y, wxs[(size_t)(j8 + 5) * 64], acc);
        acc = fmaf(w1.z, wxs[(size_t)(j8 + 6) * 64], acc);
        acc = fmaf(w1.w, wxs[(size_t)(j8 + 7) * 64], acc);
    }
    Weff[((size_t)sm * 4 + g) * 64 + k] = __float2bfloat16(acc);

    // effective bias: lane k covers j = k + 64*t
    float bacc = 0.f;
#pragma unroll
    for (int t = 0; t < 4; ++t) {
        int j = k + t * 64;
        bacc = fmaf(wrow[j],       bx[(s << 8) + j], bacc);
        bacc = fmaf(wrow[256 + j], h0[(s << 8) + j], bacc);
    }
#pragma unroll
    for (int off = 32; off > 0; off >>= 1)
        bacc += __shfl_down(bacc, off);
    if (k == 0)
        beff[g * SM + sm] = bacc + bG[sm];
}

// ---------------------------------------------------------------------------
// Kernel 2: main pass. One wave = 16(n) x 16(m) tile, all 4 gates via
// mfma_f32_16x16x32_bf16 (K=64 -> 2 k-steps/gate), LSTM cell epilogue
// in-thread (all 4 gate pre-acts for a given (n,m) land in the same lane/reg).
// Block = 4 waves covering 64 n-rows; grid = (N/64, S * M/16).
// ---------------------------------------------------------------------------
__global__ __launch_bounds__(256) void lstm_main(
    const float* __restrict__ mod, const float* __restrict__ c0,
    const bf16* __restrict__ Weff, const float* __restrict__ beff,
    float* __restrict__ out)
{
    const int wave = threadIdx.x >> 6;
    const int lane = threadIdx.x & 63;
    const int quad = lane >> 4;
    const int col  = lane & 15;

    const int n0 = blockIdx.x * 64 + wave * 16;
    const int s  = blockIdx.y >> 4;          // stream
    const int m0 = (blockIdx.y & 15) * 16;   // feature tile base

    // A fragment: A[m=lane&15][k=quad*8+j] -> batch rows, stream k-slice
    const float* arow = mod + (size_t)(n0 + col) * MODROW + s * I + quad * 8;
    bf16x8 a0 = load8_f32_to_bf16(arow);        // k in [0,32)
    bf16x8 a1 = load8_f32_to_bf16(arow + 32);   // k in [32,64)

    // B fragment: B[k=quad*8+j][n=lane&15]; Weff layout [s][m][g][k] (bf16)
    const int  mcol = m0 + col;
    const int  sm   = s * M + mcol;
    const bf16* bbase = Weff + ((size_t)sm * 4) * 64 + quad * 8;

    f32x4 acc[4];
#pragma unroll
    for (int g = 0; g < 4; ++g) {
        bf16x8 b0 = *(const bf16x8*)(bbase + (size_t)g * 64);
        bf16x8 b1 = *(const bf16x8*)(bbase + (size_t)g * 64 + 32);
        f32x4 c = {0.f, 0.f, 0.f, 0.f};
        c = __builtin_amdgcn_mfma_f32_16x16x32_bf16(a0, b0, c, 0, 0, 0);
        c = __builtin_amdgcn_mfma_f32_16x16x32_bf16(a1, b1, c, 0, 0, 0);
        acc[g] = c;
    }

    const float c0v = c0[sm];
    const float bi_ = beff[0 * SM + sm];
    const float bf_ = beff[1 * SM + sm];
    const float bg_ = beff[2 * SM + sm];
    const float bo_ = beff[3 * SM + sm];

    // D layout: row = quad*4 + r (batch), col = lane&15 (feature)
    float* obase = out + (size_t)(n0 + quad * 4) * OUTROW + sm;
#pragma unroll
    for (int r = 0; r < 4; ++r) {
        float iv = sigmoid_f(acc[0][r] + bi_);
        float fv = sigmoid_f(acc[1][r] + bf_);
        float gv = tanh_f(acc[2][r] + bg_);
        float ov = sigmoid_f(acc[3][r] + bo_);
        float cc = fv * c0v + iv * gv;
        float hv = ov * tanh_f(cc);
        obase[(size_t)r * OUTROW] = hv;
    }
}

extern "C" void kernel_launch(void* const* d_in, const int* in_sizes, int n_in,
                              void* d_out, int out_size, void* d_ws, size_t ws_size,
                              hipStream_t stream) {
    const float* mod = (const float*)d_in[0];
    const float* h0  = (const float*)d_in[1];
    const float* c0  = (const float*)d_in[2];
    const float* Wx  = (const float*)d_in[3];
    const float* bx  = (const float*)d_in[4];
    const float* Wi  = (const float*)d_in[5];
    const float* bi  = (const float*)d_in[6];
    const float* Wf  = (const float*)d_in[7];
    const float* bfv = (const float*)d_in[8];
    const float* Wg  = (const float*)d_in[9];
    const float* bg  = (const float*)d_in[10];
    const float* Wo  = (const float*)d_in[11];
    const float* bo  = (const float*)d_in[12];
    float* out = (float*)d_out;

    // workspace: Weff (bf16, S*M*4*64 = 1 MiB) | beff (fp32, 32 KiB)
    bf16*  Weff = (bf16*)d_ws;
    float* beff = (float*)((char*)d_ws + (size_t)SM * 4 * 64 * sizeof(bf16));

    precompute_kernel<<<SM, 256, 0, stream>>>(Wx, bx, Wi, bi, Wf, bfv,
                                              Wg, bg, Wo, bo, h0, Weff, beff);
    lstm_main<<<dim3(N / 64, S * (M / 16)), 256, 0, stream>>>(mod, c0, Weff, beff, out);
}

// Round 4
// 278.246 us; speedup vs baseline: 1.3517x; 1.3517x over previous
//
#include <hip/hip_runtime.h>
#include <hip/hip_bf16.h>

using bf16 = __hip_bfloat16;
typedef __attribute__((ext_vector_type(8))) short bf16x8;
typedef __attribute__((ext_vector_type(4))) float f32x4;

// Problem constants
constexpr int S = 8, I = 64, M = 256, N = 16384;
constexpr int SM = S * M;       // 2048
constexpr int MODROW = S * I;   // 512  fp32 elements per modulation row
constexpr int OUTROW = S * M;   // 2048 fp32 elements per output row
constexpr int TILES = 8;        // 16-row n-tiles per wave in the main kernel

__device__ __forceinline__ short f2bf_s(float f) {
    union { bf16 b; short s; } u; u.b = __float2bfloat16(f); return u.s;
}
// load 8 consecutive fp32 -> bf16x8 MFMA fragment slice
__device__ __forceinline__ bf16x8 cvt8(const float* p) {
    const float4 x = ((const float4*)p)[0];
    const float4 y = ((const float4*)p)[1];
    bf16x8 r;
    r[0] = f2bf_s(x.x); r[1] = f2bf_s(x.y); r[2] = f2bf_s(x.z); r[3] = f2bf_s(x.w);
    r[4] = f2bf_s(y.x); r[5] = f2bf_s(y.y); r[6] = f2bf_s(y.z); r[7] = f2bf_s(y.w);
    return r;
}

__device__ __forceinline__ float sigmoid_f(float x) {
    return __builtin_amdgcn_rcpf(1.f + __expf(-x));
}
__device__ __forceinline__ float tanh_f(float x) {
    return 2.f * __builtin_amdgcn_rcpf(1.f + __expf(-2.f * x)) - 1.f;
}

// ---------------------------------------------------------------------------
// Kernel 1 v2: Weff[s][m][g][k] = sum_j WG[s][m][j]*Wx[s][j][k]  (bf16 out)
//              beff[g][sm]      = bG + WG[:, :256]·bx + WG[:, 256:]·h0 (fp32)
// One wave per (s, g, 4-m chunk): WG row addresses are block-uniform ->
// scalar loads; each Wx lane-load feeds 4 independent FMA accumulators.
// grid = 8*4*64 = 2048 blocks x 64 threads.
// ---------------------------------------------------------------------------
__global__ __launch_bounds__(64) void precompute_kernel(
    const float* __restrict__ Wx, const float* __restrict__ bx,
    const float* __restrict__ Wi, const float* __restrict__ bi,
    const float* __restrict__ Wf, const float* __restrict__ bfv,
    const float* __restrict__ Wg, const float* __restrict__ bg,
    const float* __restrict__ Wo, const float* __restrict__ bo,
    const float* __restrict__ h0,
    bf16* __restrict__ Weff, float* __restrict__ beff)
{
    const int blk = blockIdx.x;      // (s<<8) | (g<<6) | mc
    const int mc  = blk & 63;        // 4-feature chunk within stream
    const int g   = (blk >> 6) & 3;
    const int s   = blk >> 8;
    const int k   = threadIdx.x;     // lane = I index

    const float* WG = (g == 0) ? Wi : (g == 1) ? Wf : (g == 2) ? Wg : Wo;
    const float* bG = (g == 0) ? bi : (g == 1) ? bfv : (g == 2) ? bg : bo;

    const int sm0 = s * 256 + mc * 4;
    const float* w0 = WG + (size_t)(sm0 + 0) * 512;   // block-uniform rows
    const float* w1 = WG + (size_t)(sm0 + 1) * 512;
    const float* w2 = WG + (size_t)(sm0 + 2) * 512;
    const float* w3 = WG + (size_t)(sm0 + 3) * 512;
    const float* wxs = Wx + (size_t)s * (256 * 64) + k;

    float a0 = 0.f, a1 = 0.f, a2 = 0.f, a3 = 0.f;
    for (int j = 0; j < 256; j += 8) {
#pragma unroll
        for (int u = 0; u < 8; ++u) {
            const float wx = wxs[(size_t)(j + u) * 64];
            a0 = fmaf(w0[j + u], wx, a0);
            a1 = fmaf(w1[j + u], wx, a1);
            a2 = fmaf(w2[j + u], wx, a2);
            a3 = fmaf(w3[j + u], wx, a3);
        }
    }
    Weff[((size_t)(sm0 + 0) * 4 + g) * 64 + k] = __float2bfloat16(a0);
    Weff[((size_t)(sm0 + 1) * 4 + g) * 64 + k] = __float2bfloat16(a1);
    Weff[((size_t)(sm0 + 2) * 4 + g) * 64 + k] = __float2bfloat16(a2);
    Weff[((size_t)(sm0 + 3) * 4 + g) * 64 + k] = __float2bfloat16(a3);

    // effective bias (x-bias fold + h0 fold); lane k covers j = k + 64t
    float b0 = 0.f, b1 = 0.f, b2 = 0.f, b3 = 0.f;
#pragma unroll
    for (int t = 0; t < 4; ++t) {
        const int j = k + t * 64;
        const float xb = bx[(s << 8) + j];
        const float xh = h0[(s << 8) + j];
        b0 = fmaf(w0[j], xb, b0); b0 = fmaf(w0[256 + j], xh, b0);
        b1 = fmaf(w1[j], xb, b1); b1 = fmaf(w1[256 + j], xh, b1);
        b2 = fmaf(w2[j], xb, b2); b2 = fmaf(w2[256 + j], xh, b2);
        b3 = fmaf(w3[j], xb, b3); b3 = fmaf(w3[256 + j], xh, b3);
    }
#pragma unroll
    for (int off = 32; off > 0; off >>= 1) {
        b0 += __shfl_down(b0, off);
        b1 += __shfl_down(b1, off);
        b2 += __shfl_down(b2, off);
        b3 += __shfl_down(b3, off);
    }
    if (k == 0) {
        beff[g * SM + sm0 + 0] = b0 + bG[sm0 + 0];
        beff[g * SM + sm0 + 1] = b1 + bG[sm0 + 1];
        beff[g * SM + sm0 + 2] = b2 + bG[sm0 + 2];
        beff[g * SM + sm0 + 3] = b3 + bG[sm0 + 3];
    }
}

// ---------------------------------------------------------------------------
// Kernel 2 v2: A = Weff (D rows = features -> float4 stores), B = mod.
// Each wave holds 8 A-fragments (4 gates x 2 k-steps) and loops over TILES
// n-tiles with software-pipelined mod prefetch. Block = 4 waves covering a
// 64-feature range (256 B/row contiguous stores across the block).
// grid = (N/(16*TILES), S*4), block = 256.
// ---------------------------------------------------------------------------
__global__ __launch_bounds__(256) void lstm_main(
    const float* __restrict__ mod, const float* __restrict__ c0,
    const bf16* __restrict__ Weff, const float* __restrict__ beff,
    float* __restrict__ out)
{
    const int wave = threadIdx.x >> 6;
    const int lane = threadIdx.x & 63;
    const int quad = lane >> 4;
    const int col  = lane & 15;

    const int s  = blockIdx.y >> 2;           // stream
    const int mq = blockIdx.y & 3;            // 64-feature quarter
    const int m0 = mq * 64 + wave * 16;       // wave's 16-feature tile
    const int sm_tile = s * 256 + m0;

    // A fragments: A[m = lane&15][k = quad*8 + j]; Weff layout [s][m][g][k]
    const bf16* abase = Weff + ((size_t)(sm_tile + col) * 4) * 64 + quad * 8;
    bf16x8 afrag[4][2];
#pragma unroll
    for (int g = 0; g < 4; ++g) {
        afrag[g][0] = *(const bf16x8*)(abase + (size_t)g * 64);
        afrag[g][1] = *(const bf16x8*)(abase + (size_t)g * 64 + 32);
    }

    // n-invariant epilogue constants: this thread owns m = sm4 + {0..3}
    const int sm4 = sm_tile + quad * 4;
    const f32x4 c0v = *(const f32x4*)(c0 + sm4);
    const f32x4 biv = *(const f32x4*)(beff + 0 * SM + sm4);
    const f32x4 bfv = *(const f32x4*)(beff + 1 * SM + sm4);
    const f32x4 bgv = *(const f32x4*)(beff + 2 * SM + sm4);
    const f32x4 bov = *(const f32x4*)(beff + 3 * SM + sm4);

    const int nbase = blockIdx.x * (16 * TILES);
    const float* brow0 = mod + (size_t)(nbase + col) * MODROW + s * I + quad * 8;

    // prime the pipeline
    bf16x8 b0 = cvt8(brow0);
    bf16x8 b1 = cvt8(brow0 + 32);

#pragma unroll
    for (int t = 0; t < TILES; ++t) {
        bf16x8 nb0, nb1;
        if (t + 1 < TILES) {                       // prefetch next n-tile
            const float* brow = brow0 + (size_t)(t + 1) * 16 * MODROW;
            nb0 = cvt8(brow);
            nb1 = cvt8(brow + 32);
        }

        f32x4 acc[4];
#pragma unroll
        for (int g = 0; g < 4; ++g) {
            f32x4 c = {0.f, 0.f, 0.f, 0.f};
            c = __builtin_amdgcn_mfma_f32_16x16x32_bf16(afrag[g][0], b0, c, 0, 0, 0);
            c = __builtin_amdgcn_mfma_f32_16x16x32_bf16(afrag[g][1], b1, c, 0, 0, 0);
            acc[g] = c;
        }

        // epilogue: D[row = m = quad*4+r][col = n]; thread stores float4 in m
        const int n = nbase + t * 16 + col;
        f32x4 hv;
#pragma unroll
        for (int r = 0; r < 4; ++r) {
            const float iv = sigmoid_f(acc[0][r] + biv[r]);
            const float fv = sigmoid_f(acc[1][r] + bfv[r]);
            const float gv = tanh_f(acc[2][r] + bgv[r]);
            const float ov = sigmoid_f(acc[3][r] + bov[r]);
            const float cc = fv * c0v[r] + iv * gv;
            hv[r] = ov * tanh_f(cc);
        }
        *(f32x4*)(out + (size_t)n * OUTROW + sm4) = hv;

        if (t + 1 < TILES) { b0 = nb0; b1 = nb1; }
    }
}

extern "C" void kernel_launch(void* const* d_in, const int* in_sizes, int n_in,
                              void* d_out, int out_size, void* d_ws, size_t ws_size,
                              hipStream_t stream) {
    const float* mod = (const float*)d_in[0];
    const float* h0  = (const float*)d_in[1];
    const float* c0  = (const float*)d_in[2];
    const float* Wx  = (const float*)d_in[3];
    const float* bx  = (const float*)d_in[4];
    const float* Wi  = (const float*)d_in[5];
    const float* bi  = (const float*)d_in[6];
    const float* Wf  = (const float*)d_in[7];
    const float* bfv = (const float*)d_in[8];
    const float* Wg  = (const float*)d_in[9];
    const float* bg  = (const float*)d_in[10];
    const float* Wo  = (const float*)d_in[11];
    const float* bo  = (const float*)d_in[12];
    float* out = (float*)d_out;

    // workspace: Weff (bf16, S*M*4*64 = 1 MiB) | beff (fp32, 32 KiB)
    bf16*  Weff = (bf16*)d_ws;
    float* beff = (float*)((char*)d_ws + (size_t)SM * 4 * 64 * sizeof(bf16));

    precompute_kernel<<<2048, 64, 0, stream>>>(Wx, bx, Wi, bi, Wf, bfv,
                                               Wg, bg, Wo, bo, h0, Weff, beff);
    lstm_main<<<dim3(N / (16 * TILES), S * 4), 256, 0, stream>>>(
        mod, c0, Weff, beff, out);
}

// Round 5
// 254.722 us; speedup vs baseline: 1.4766x; 1.0924x over previous
//
#include <hip/hip_runtime.h>
#include <hip/hip_bf16.h>

using bf16 = __hip_bfloat16;
typedef __attribute__((ext_vector_type(8))) short bf16x8;
typedef __attribute__((ext_vector_type(4))) float f32x4;

// Problem constants
constexpr int S = 8, I = 64, M = 256, N = 16384;
constexpr int SM = S * M;       // 2048
constexpr int MODROW = S * I;   // 512  elements per modulation row
constexpr int OUTROW = S * M;   // 2048 fp32 elements per output row
constexpr int TILES = 8;        // 16-row n-tiles per wave in the main kernel

__device__ __forceinline__ short f2bf_s(float f) {
    union { bf16 b; short s; } u; u.b = __float2bfloat16(f); return u.s;
}
// load 8 consecutive fp32 -> bf16x8 fragment slice (RNE)
__device__ __forceinline__ bf16x8 cvt8(const float* p) {
    const float4 x = ((const float4*)p)[0];
    const float4 y = ((const float4*)p)[1];
    bf16x8 r;
    r[0] = f2bf_s(x.x); r[1] = f2bf_s(x.y); r[2] = f2bf_s(x.z); r[3] = f2bf_s(x.w);
    r[4] = f2bf_s(y.x); r[5] = f2bf_s(y.y); r[6] = f2bf_s(y.z); r[7] = f2bf_s(y.w);
    return r;
}

__device__ __forceinline__ float sigmoid_f(float x) {
    return __builtin_amdgcn_rcpf(1.f + __expf(-x));
}
__device__ __forceinline__ float tanh_f(float x) {
    return 2.f * __builtin_amdgcn_rcpf(1.f + __expf(-2.f * x)) - 1.f;
}

// ---------------------------------------------------------------------------
// Kernel 0: mod fp32 -> bf16, one shot. 8 elements/thread.
// grid = N*MODROW/(8*256) = 4096 blocks.
// ---------------------------------------------------------------------------
__global__ __launch_bounds__(256) void cvt_mod(
    const float* __restrict__ in, bf16* __restrict__ outb)
{
    const size_t i = ((size_t)blockIdx.x * 256 + threadIdx.x) * 8;
    *(bf16x8*)(outb + i) = cvt8(in + i);
}

// ---------------------------------------------------------------------------
// Kernel 1: Weff[s][m][g][k] = sum_j WG[s][m][j]*Wx[s][j][k]  (bf16 out)
//           beff[g][sm]      = bG + WG[:, :256]·bx + WG[:, 256:]·h0 (fp32)
// One wave per (s, g, 4-m chunk); WG rows are block-uniform -> scalar loads.
// ---------------------------------------------------------------------------
__global__ __launch_bounds__(64) void precompute_kernel(
    const float* __restrict__ Wx, const float* __restrict__ bx,
    const float* __restrict__ Wi, const float* __restrict__ bi,
    const float* __restrict__ Wf, const float* __restrict__ bfv,
    const float* __restrict__ Wg, const float* __restrict__ bg,
    const float* __restrict__ Wo, const float* __restrict__ bo,
    const float* __restrict__ h0,
    bf16* __restrict__ Weff, float* __restrict__ beff)
{
    const int blk = blockIdx.x;      // (s<<8) | (g<<6) | mc
    const int mc  = blk & 63;
    const int g   = (blk >> 6) & 3;
    const int s   = blk >> 8;
    const int k   = threadIdx.x;

    const float* WG = (g == 0) ? Wi : (g == 1) ? Wf : (g == 2) ? Wg : Wo;
    const float* bG = (g == 0) ? bi : (g == 1) ? bfv : (g == 2) ? bg : bo;

    const int sm0 = s * 256 + mc * 4;
    const float* w0 = WG + (size_t)(sm0 + 0) * 512;
    const float* w1 = WG + (size_t)(sm0 + 1) * 512;
    const float* w2 = WG + (size_t)(sm0 + 2) * 512;
    const float* w3 = WG + (size_t)(sm0 + 3) * 512;
    const float* wxs = Wx + (size_t)s * (256 * 64) + k;

    float a0 = 0.f, a1 = 0.f, a2 = 0.f, a3 = 0.f;
    for (int j = 0; j < 256; j += 8) {
#pragma unroll
        for (int u = 0; u < 8; ++u) {
            const float wx = wxs[(size_t)(j + u) * 64];
            a0 = fmaf(w0[j + u], wx, a0);
            a1 = fmaf(w1[j + u], wx, a1);
            a2 = fmaf(w2[j + u], wx, a2);
            a3 = fmaf(w3[j + u], wx, a3);
        }
    }
    Weff[((size_t)(sm0 + 0) * 4 + g) * 64 + k] = __float2bfloat16(a0);
    Weff[((size_t)(sm0 + 1) * 4 + g) * 64 + k] = __float2bfloat16(a1);
    Weff[((size_t)(sm0 + 2) * 4 + g) * 64 + k] = __float2bfloat16(a2);
    Weff[((size_t)(sm0 + 3) * 4 + g) * 64 + k] = __float2bfloat16(a3);

    float b0 = 0.f, b1 = 0.f, b2 = 0.f, b3 = 0.f;
#pragma unroll
    for (int t = 0; t < 4; ++t) {
        const int j = k + t * 64;
        const float xb = bx[(s << 8) + j];
        const float xh = h0[(s << 8) + j];
        b0 = fmaf(w0[j], xb, b0); b0 = fmaf(w0[256 + j], xh, b0);
        b1 = fmaf(w1[j], xb, b1); b1 = fmaf(w1[256 + j], xh, b1);
        b2 = fmaf(w2[j], xb, b2); b2 = fmaf(w2[256 + j], xh, b2);
        b3 = fmaf(w3[j], xb, b3); b3 = fmaf(w3[256 + j], xh, b3);
    }
#pragma unroll
    for (int off = 32; off > 0; off >>= 1) {
        b0 += __shfl_down(b0, off);
        b1 += __shfl_down(b1, off);
        b2 += __shfl_down(b2, off);
        b3 += __shfl_down(b3, off);
    }
    if (k == 0) {
        beff[g * SM + sm0 + 0] = b0 + bG[sm0 + 0];
        beff[g * SM + sm0 + 1] = b1 + bG[sm0 + 1];
        beff[g * SM + sm0 + 2] = b2 + bG[sm0 + 2];
        beff[g * SM + sm0 + 3] = b3 + bG[sm0 + 3];
    }
}

// ---------------------------------------------------------------------------
// Kernel 2 (bf16-B): A = Weff (D rows = features), B = pre-converted bf16 mod.
// Bias folded into MFMA acc init. No float->bf16 cvt in the hot loop.
// ---------------------------------------------------------------------------
__global__ __launch_bounds__(256) void lstm_main_bf(
    const bf16* __restrict__ modb, const float* __restrict__ c0,
    const bf16* __restrict__ Weff, const float* __restrict__ beff,
    float* __restrict__ out)
{
    const int wave = threadIdx.x >> 6;
    const int lane = threadIdx.x & 63;
    const int quad = lane >> 4;
    const int col  = lane & 15;

    const int s  = blockIdx.y >> 2;
    const int mq = blockIdx.y & 3;
    const int m0 = mq * 64 + wave * 16;
    const int sm_tile = s * 256 + m0;

    // A fragments: A[m = lane&15][k = quad*8 + j]; Weff layout [s][m][g][k]
    const bf16* abase = Weff + ((size_t)(sm_tile + col) * 4) * 64 + quad * 8;
    bf16x8 afrag[4][2];
#pragma unroll
    for (int g = 0; g < 4; ++g) {
        afrag[g][0] = *(const bf16x8*)(abase + (size_t)g * 64);
        afrag[g][1] = *(const bf16x8*)(abase + (size_t)g * 64 + 32);
    }

    // n-invariant constants: this thread owns m = sm4 + {0..3}
    const int sm4 = sm_tile + quad * 4;
    const f32x4 c0v = *(const f32x4*)(c0 + sm4);
    f32x4 bias[4];
#pragma unroll
    for (int g = 0; g < 4; ++g)
        bias[g] = *(const f32x4*)(beff + g * SM + sm4);

    const int nbase = blockIdx.x * (16 * TILES);
    const bf16* brow0 = modb + (size_t)(nbase + col) * MODROW + s * I + quad * 8;

    bf16x8 b0 = *(const bf16x8*)(brow0);
    bf16x8 b1 = *(const bf16x8*)(brow0 + 32);

#pragma unroll
    for (int t = 0; t < TILES; ++t) {
        bf16x8 nb0, nb1;
        if (t + 1 < TILES) {
            const bf16* brow = brow0 + (size_t)(t + 1) * 16 * MODROW;
            nb0 = *(const bf16x8*)(brow);
            nb1 = *(const bf16x8*)(brow + 32);
        }

        f32x4 acc[4];
#pragma unroll
        for (int g = 0; g < 4; ++g) {
            f32x4 c = bias[g];   // bias pre-loaded into accumulator
            c = __builtin_amdgcn_mfma_f32_16x16x32_bf16(afrag[g][0], b0, c, 0, 0, 0);
            c = __builtin_amdgcn_mfma_f32_16x16x32_bf16(afrag[g][1], b1, c, 0, 0, 0);
            acc[g] = c;
        }

        const int n = nbase + t * 16 + col;
        f32x4 hv;
#pragma unroll
        for (int r = 0; r < 4; ++r) {
            const float iv = sigmoid_f(acc[0][r]);
            const float fv = sigmoid_f(acc[1][r]);
            const float gv = tanh_f(acc[2][r]);
            const float ov = sigmoid_f(acc[3][r]);
            const float cc = fv * c0v[r] + iv * gv;
            hv[r] = ov * tanh_f(cc);
        }
        *(f32x4*)(out + (size_t)n * OUTROW + sm4) = hv;

        if (t + 1 < TILES) { b0 = nb0; b1 = nb1; }
    }
}

// ---------------------------------------------------------------------------
// Kernel 2 fallback (f32-B, inline cvt) — used only if ws too small for modb.
// ---------------------------------------------------------------------------
__global__ __launch_bounds__(256) void lstm_main_f32(
    const float* __restrict__ mod, const float* __restrict__ c0,
    const bf16* __restrict__ Weff, const float* __restrict__ beff,
    float* __restrict__ out)
{
    const int wave = threadIdx.x >> 6;
    const int lane = threadIdx.x & 63;
    const int quad = lane >> 4;
    const int col  = lane & 15;

    const int s  = blockIdx.y >> 2;
    const int mq = blockIdx.y & 3;
    const int m0 = mq * 64 + wave * 16;
    const int sm_tile = s * 256 + m0;

    const bf16* abase = Weff + ((size_t)(sm_tile + col) * 4) * 64 + quad * 8;
    bf16x8 afrag[4][2];
#pragma unroll
    for (int g = 0; g < 4; ++g) {
        afrag[g][0] = *(const bf16x8*)(abase + (size_t)g * 64);
        afrag[g][1] = *(const bf16x8*)(abase + (size_t)g * 64 + 32);
    }

    const int sm4 = sm_tile + quad * 4;
    const f32x4 c0v = *(const f32x4*)(c0 + sm4);
    f32x4 bias[4];
#pragma unroll
    for (int g = 0; g < 4; ++g)
        bias[g] = *(const f32x4*)(beff + g * SM + sm4);

    const int nbase = blockIdx.x * (16 * TILES);
    const float* brow0 = mod + (size_t)(nbase + col) * MODROW + s * I + quad * 8;

    bf16x8 b0 = cvt8(brow0);
    bf16x8 b1 = cvt8(brow0 + 32);

#pragma unroll
    for (int t = 0; t < TILES; ++t) {
        bf16x8 nb0, nb1;
        if (t + 1 < TILES) {
            const float* brow = brow0 + (size_t)(t + 1) * 16 * MODROW;
            nb0 = cvt8(brow);
            nb1 = cvt8(brow + 32);
        }
        f32x4 acc[4];
#pragma unroll
        for (int g = 0; g < 4; ++g) {
            f32x4 c = bias[g];
            c = __builtin_amdgcn_mfma_f32_16x16x32_bf16(afrag[g][0], b0, c, 0, 0, 0);
            c = __builtin_amdgcn_mfma_f32_16x16x32_bf16(afrag[g][1], b1, c, 0, 0, 0);
            acc[g] = c;
        }
        const int n = nbase + t * 16 + col;
        f32x4 hv;
#pragma unroll
        for (int r = 0; r < 4; ++r) {
            const float iv = sigmoid_f(acc[0][r]);
            const float fv = sigmoid_f(acc[1][r]);
            const float gv = tanh_f(acc[2][r]);
            const float ov = sigmoid_f(acc[3][r]);
            const float cc = fv * c0v[r] + iv * gv;
            hv[r] = ov * tanh_f(cc);
        }
        *(f32x4*)(out + (size_t)n * OUTROW + sm4) = hv;
        if (t + 1 < TILES) { b0 = nb0; b1 = nb1; }
    }
}

extern "C" void kernel_launch(void* const* d_in, const int* in_sizes, int n_in,
                              void* d_out, int out_size, void* d_ws, size_t ws_size,
                              hipStream_t stream) {
    const float* mod = (const float*)d_in[0];
    const float* h0  = (const float*)d_in[1];
    const float* c0  = (const float*)d_in[2];
    const float* Wx  = (const float*)d_in[3];
    const float* bx  = (const float*)d_in[4];
    const float* Wi  = (const float*)d_in[5];
    const float* bi  = (const float*)d_in[6];
    const float* Wf  = (const float*)d_in[7];
    const float* bfv = (const float*)d_in[8];
    const float* Wg  = (const float*)d_in[9];
    const float* bg  = (const float*)d_in[10];
    const float* Wo  = (const float*)d_in[11];
    const float* bo  = (const float*)d_in[12];
    float* out = (float*)d_out;

    // ws layout: Weff bf16 (1 MiB) | beff fp32 (32 KiB) | modb bf16 (16 MiB)
    const size_t weff_b = (size_t)SM * 4 * 64 * sizeof(bf16);   // 1,048,576
    const size_t beff_b = (size_t)4 * SM * sizeof(float);       //    32,768
    const size_t modb_b = (size_t)N * MODROW * sizeof(bf16);    // 16,777,216
    bf16*  Weff = (bf16*)d_ws;
    float* beff = (float*)((char*)d_ws + weff_b);
    bf16*  modb = (bf16*)((char*)d_ws + weff_b + beff_b);

    precompute_kernel<<<2048, 64, 0, stream>>>(Wx, bx, Wi, bi, Wf, bfv,
                                               Wg, bg, Wo, bo, h0, Weff, beff);

    if (ws_size >= weff_b + beff_b + modb_b) {
        cvt_mod<<<(N * MODROW) / (8 * 256), 256, 0, stream>>>(mod, modb);
        lstm_main_bf<<<dim3(N / (16 * TILES), S * 4), 256, 0, stream>>>(
            modb, c0, Weff, beff, out);
    } else {
        lstm_main_f32<<<dim3(N / (16 * TILES), S * 4), 256, 0, stream>>>(
            mod, c0, Weff, beff, out);
    }
}